// Round 12
// baseline (6658.099 us; speedup 1.0000x reference)
//
#include <hip/hip_runtime.h>

#define T_STEPS 1024
#define N_IN    128
#define H       256
#define N_OUT   64
#define WARM    10

// Force block-uniform mask into SGPRs: the ffs/clear chain becomes scalar
// (1 cy, no VALU, no VGPR pressure) and loads batch properly.
__device__ __forceinline__ unsigned long long uniform64(unsigned long long m) {
  unsigned int lo = __builtin_amdgcn_readfirstlane((unsigned int)m);
  unsigned int hi = __builtin_amdgcn_readfirstlane((unsigned int)(m >> 32));
  return ((unsigned long long)hi << 32) | lo;
}

// R7/R11-validated bit-exact sparse walk: single accumulator, strict ascending
// j (== numpy's dense k-sequential chain; skipped terms contribute exactly
// +0.0f). 16 independent loads per batch issue together; mask chain is SCALAR.
__device__ __forceinline__ float walk16(const unsigned long long* __restrict__ m4,
                                        const float* __restrict__ base,
                                        int sjj, int sii, int i) {
  float a = 0.f;
#pragma unroll
  for (int w = 0; w < 4; ++w) {
    unsigned long long m = uniform64(m4[w]);
    const float* bp = base + (size_t)(w * 64) * sjj + (size_t)i * sii;
    while (m) {
      float t0,t1,t2,t3,t4,t5,t6,t7,t8,t9,t10,t11,t12,t13,t14,t15;
#define GRAB(tk) { int j = m ? (__ffsll(m) - 1) : 0;            \
                   float v = bp[(size_t)j * sjj];               \
                   tk = m ? v : 0.0f;                           \
                   m &= m - 1; }
      GRAB(t0)  GRAB(t1)  GRAB(t2)  GRAB(t3)
      GRAB(t4)  GRAB(t5)  GRAB(t6)  GRAB(t7)
      GRAB(t8)  GRAB(t9)  GRAB(t10) GRAB(t11)
      GRAB(t12) GRAB(t13) GRAB(t14) GRAB(t15)
#undef GRAB
      a += t0;  a += t1;  a += t2;  a += t3;
      a += t4;  a += t5;  a += t6;  a += t7;
      a += t8;  a += t9;  a += t10; a += t11;
      a += t12; a += t13; a += t14; a += t15;
    }
  }
  return a;
}

// ---------- pre 1 (R8-validated): xw[b][t][i] = sum_k x[b,t,k]*W_in[i,k] ----------
__launch_bounds__(256)
__global__ void srnn_xw(const float* __restrict__ x,
                        const float* __restrict__ Win,
                        float* __restrict__ xw) {
  __shared__ float win[N_IN * H];
  __shared__ float xt[32][N_IN];
  const int tid = (int)threadIdx.x;
  const int b  = (int)blockIdx.x >> 5;
  const int t0 = ((int)blockIdx.x & 31) * 32;
  for (int q = tid; q < H * N_IN; q += 256) {
    int i2 = q >> 7, k = q & (N_IN - 1);
    win[k * H + i2] = Win[q];
  }
  for (int q = tid; q < 32 * N_IN; q += 256) {
    int r = q >> 7, k = q & (N_IN - 1);
    xt[r][k] = x[((size_t)b * T_STEPS + t0 + r) * N_IN + k];
  }
  __syncthreads();
  const int i = tid;
  for (int r = 0; r < 32; r += 4) {
    float a0 = 0.f, a1 = 0.f, a2 = 0.f, a3 = 0.f;
#pragma unroll 16
    for (int k = 0; k < N_IN; ++k) {
      float wv = win[k * H + i];
      a0 = fmaf(xt[r + 0][k], wv, a0);
      a1 = fmaf(xt[r + 1][k], wv, a1);
      a2 = fmaf(xt[r + 2][k], wv, a2);
      a3 = fmaf(xt[r + 3][k], wv, a3);
    }
    xw[((size_t)b * T_STEPS + t0 + r + 0) * H + i] = a0;
    xw[((size_t)b * T_STEPS + t0 + r + 1) * H + i] = a1;
    xw[((size_t)b * T_STEPS + t0 + r + 2) * H + i] = a2;
    xw[((size_t)b * T_STEPS + t0 + r + 3) * H + i] = a3;
  }
}

// ---------- pre 2 (R7-validated): transpose Wh1/W12/Wh2 (HxH) + Wout ----------
__global__ void srnn_prep(const float* __restrict__ Wh1,
                          const float* __restrict__ W12,
                          const float* __restrict__ Wh2,
                          const float* __restrict__ Wout,
                          float* __restrict__ ws) {
  int idx = blockIdx.x * 256 + (int)threadIdx.x;     // 0 .. 212991
  if (idx < 3 * H * H) {
    int mat = idx >> 16;
    int rem = idx & (H * H - 1);
    int j = rem >> 8;
    int i = rem & (H - 1);
    const float* src = (mat == 0) ? Wh1 : (mat == 1) ? W12 : Wh2;
    ws[idx] = src[i * H + j];          // WT[j][i]
  } else {
    int rem = idx - 3 * H * H;
    int j = rem >> 6;
    int o = rem & (N_OUT - 1);
    ws[idx] = Wout[o * H + j];         // WoutT[j][o]
  }
}

// ---------- pipelined scan (R11-validated schedule): ONE walk-latency per step ----------
// L(t):  G0: w12(t)->reg | G1: h2(t) | G2: h1(t+1) | G3: readout(t-1) [+x stage]
// M(t):  u2(t) (ballot s2) then u1(t+1) (ballot s1), both on tid<256.
template<int MODE>   // 0: xw precomputed; 1: in-scan x-dot via win_lds
__launch_bounds__(1024)
__global__ void srnn_scan3(const float* __restrict__ x,
                           const float* __restrict__ xw,
                           const float* __restrict__ Win,
                           const float* __restrict__ bin_p, const float* __restrict__ bh1_p,
                           const float* __restrict__ b12_p, const float* __restrict__ bh2_p,
                           const float* __restrict__ Wh1b, int h1j, int h1i,
                           const float* __restrict__ W12b, int c12j, int c12i,
                           const float* __restrict__ Wh2b, int h2j, int h2i,
                           const float* __restrict__ Wob,  int woj, int woi,
                           const float* __restrict__ bo_p,
                           float* __restrict__ out) {
  __shared__ float h1d[H], h2d[H];
  __shared__ unsigned long long s1m[2][4], s2m[2][4];
  __shared__ float win_lds[(MODE == 1) ? (N_IN * 257) : 1];   // stride-257: conflict-free
  __shared__ float xs[(MODE == 1) ? 2 : 1][N_IN];

  const int tid = (int)threadIdx.x;
  const int g   = tid >> 8;
  const int i   = tid & 255;
  const int b   = (int)blockIdx.x;

  if (MODE == 1) {
    for (int q = tid; q < H * N_IN; q += 1024) {
      int i2 = q >> 7, k = q & (N_IN - 1);
      win_lds[k * 257 + i2] = Win[q];
    }
    if (tid < N_IN) xs[0][tid] = x[(size_t)b * (T_STEPS * N_IN) + tid];
  }
  if (tid < 4)       { s1m[0][tid] = 0ull; s2m[0][tid] = 0ull; }
  else if (tid < 8)  { s1m[1][tid - 4] = 0ull; s2m[1][tid - 4] = 0ull; }

  const float bin_i = (tid < H) ? bin_p[i] : 0.f;
  const float bh1_i = (tid < H) ? bh1_p[i] : 0.f;
  const float b12_i = (tid < H) ? b12_p[i] : 0.f;
  const float bh2_i = (tid < H) ? bh2_p[i] : 0.f;
  const float bo_o  = (g == 3 && i < N_OUT) ? bo_p[i] : 0.f;

  float m1 = 0.f, m2 = 0.f, acc = 0.f, c12v = 0.f, xv_next = 0.f;

  __syncthreads();   // staging + mask zero visible

  // ---- prologue "M(-1)": u1(0) = ((((0.9*0)+xdot)+b_in)+0.0)+b_h1; ballot s1(0)
  if (tid < H) {
    float xv0;
    if (MODE == 0) {
      xv0     = xw[((size_t)b * T_STEPS + 0) * H + i];
      xv_next = xw[((size_t)b * T_STEPS + 1) * H + i];
    } else {
      float a = 0.f;
#pragma unroll 16
      for (int k = 0; k < N_IN; ++k)
        a = fmaf(xs[0][k], win_lds[k * 257 + i], a);
      xv0 = a;
    }
    float u1 = 0.9f * m1;
    u1 = u1 + xv0;
    u1 = u1 + bin_i;
    u1 = u1 + 0.0f;          // h1 gather of zero spikes == +0.0 (np adds it too)
    u1 = u1 + bh1_i;
    bool sp = (u1 - 1.0f) > 0.0f;
    m1 = u1 - (sp ? 1.0f : 0.0f);
    unsigned long long bm = __ballot(sp);
    if ((tid & 63) == 0) s1m[0][tid >> 6] = bm;
  }
  __syncthreads();

  for (int t = 0; t < T_STEPS; ++t) {
    const int cb = t & 1;
    const int pb = cb ^ 1;

    // ---- L(t): all four walks concurrent (16 waves busy)
    if (g == 0) {
      c12v = walk16(s1m[cb], W12b, c12j, c12i, i);          // stays in register
    } else if (g == 1) {
      h2d[i] = walk16(s2m[pb], Wh2b, h2j, h2i, i);          // s2(t-1)
    } else if (g == 2) {
      h1d[i] = walk16(s1m[cb], Wh1b, h1j, h1i, i);          // for u1(t+1)
    } else {
      if (i < N_OUT) {
        if (t > WARM) {                                     // readout of s2(t-1)
          float d = walk16(s2m[pb], Wob, woj, woi, i);
          acc = acc + (d + bo_o);
        }
      } else if (MODE == 1 && i >= 64 && i < 64 + N_IN && t + 1 < T_STEPS) {
        xs[pb][i - 64] = x[(size_t)b * (T_STEPS * N_IN) + (size_t)(t + 1) * N_IN + (i - 64)];
      }
    }
    __syncthreads();

    // ---- M(t): u2(t) then u1(t+1), two ballots (tid<256)
    if (tid < H) {
      float u2 = 0.9f * m2;
      u2 = u2 + c12v;
      u2 = u2 + b12_i;
      u2 = u2 + h2d[i];
      u2 = u2 + bh2_i;
      bool sp2 = (u2 - 1.0f) > 0.0f;
      m2 = u2 - (sp2 ? 1.0f : 0.0f);
      unsigned long long bm2 = __ballot(sp2);
      if ((tid & 63) == 0) s2m[cb][tid >> 6] = bm2;

      if (t + 1 < T_STEPS) {
        float xv;
        if (MODE == 0) {
          xv = xv_next;
        } else {
          float a = 0.f;
#pragma unroll 16
          for (int k = 0; k < N_IN; ++k)
            a = fmaf(xs[pb][k], win_lds[k * 257 + i], a);
          xv = a;
        }
        float u1 = 0.9f * m1;
        u1 = u1 + xv;
        u1 = u1 + bin_i;
        u1 = u1 + h1d[i];
        u1 = u1 + bh1_i;
        bool sp1 = (u1 - 1.0f) > 0.0f;
        m1 = u1 - (sp1 ? 1.0f : 0.0f);
        unsigned long long bm1 = __ballot(sp1);
        if ((tid & 63) == 0) s1m[pb][tid >> 6] = bm1;
        if (MODE == 0 && t + 2 < T_STEPS)
          xv_next = xw[((size_t)b * T_STEPS + (t + 2)) * H + i];
      }
    }
    __syncthreads();
  }

  // ---- epilogue: readout of s2(1023) (lives in buffer (1023)&1 = 1)
  if (g == 3 && i < N_OUT) {
    float d = walk16(s2m[1], Wob, woj, woi, i);
    acc = acc + (d + bo_o);
    out[(size_t)b * N_OUT + i] = acc / 1014.0f;
  }
}

// ---------- launch ----------
extern "C" void kernel_launch(void* const* d_in, const int* in_sizes, int n_in,
                              void* d_out, int out_size, void* d_ws, size_t ws_size,
                              hipStream_t stream) {
  const float* x     = (const float*)d_in[0];
  const float* W_in  = (const float*)d_in[1];
  const float* b_in  = (const float*)d_in[2];
  const float* W_h1  = (const float*)d_in[3];
  const float* b_h1  = (const float*)d_in[4];
  const float* W_12  = (const float*)d_in[5];
  const float* b_12  = (const float*)d_in[6];
  const float* W_h2  = (const float*)d_in[7];
  const float* b_h2  = (const float*)d_in[8];
  const float* W_out = (const float*)d_in[9];
  const float* b_out = (const float*)d_in[10];
  float* out = (float*)d_out;
  float* wsf = (float*)d_ws;

  const size_t XW_FLOATS = (size_t)256 * T_STEPS * H;          // 67,108,864
  const size_t TR_FLOATS = (size_t)3 * H * H + H * N_OUT;      // 212,992
  const size_t need0 = (XW_FLOATS + TR_FLOATS) * sizeof(float);
  const size_t need1 = TR_FLOATS * sizeof(float);

  if (ws_size >= need0) {
    float* xwp = wsf;
    float* tr  = wsf + XW_FLOATS;
    srnn_xw<<<8192, 256, 0, stream>>>(x, W_in, xwp);
    srnn_prep<<<(int)(TR_FLOATS / 256), 256, 0, stream>>>(W_h1, W_12, W_h2, W_out, tr);
    srnn_scan3<0><<<256, 1024, 0, stream>>>(
        x, xwp, W_in, b_in, b_h1, b_12, b_h2,
        tr,                       H, 1,        // Wh1T[j][i]
        tr + (size_t)H * H,       H, 1,        // W12T
        tr + (size_t)2 * H * H,   H, 1,        // Wh2T
        tr + (size_t)3 * H * H,   N_OUT, 1,    // WoutT[j][o]
        b_out, out);
  } else if (ws_size >= need1) {
    float* tr = wsf;
    srnn_prep<<<(int)(TR_FLOATS / 256), 256, 0, stream>>>(W_h1, W_12, W_h2, W_out, tr);
    srnn_scan3<1><<<256, 1024, 0, stream>>>(
        x, nullptr, W_in, b_in, b_h1, b_12, b_h2,
        tr,                       H, 1,
        tr + (size_t)H * H,       H, 1,
        tr + (size_t)2 * H * H,   H, 1,
        tr + (size_t)3 * H * H,   N_OUT, 1,
        b_out, out);
  } else {
    srnn_scan3<1><<<256, 1024, 0, stream>>>(
        x, nullptr, W_in, b_in, b_h1, b_12, b_h2,
        W_h1,  1, H,                 // original layouts (strided walks)
        W_12,  1, H,
        W_h2,  1, H,
        W_out, 1, H,
        b_out, out);
  }
}

// Round 13
// 3095.330 us; speedup vs baseline: 2.1510x; 2.1510x over previous
//
#include <hip/hip_runtime.h>

#define T_STEPS 1024
#define N_IN    128
#define H       256
#define N_OUT   64
#define WARM    10

// ===================== asm walk: bit-exact compact-list gather ==============
// Index list (built in the C phase) holds spiking-neuron indices in ASCENDING
// order, padded to a multiple of 32 with index 256 -> a zero row appended to
// each transposed weight matrix (adds +0.0f, an exact identity). Single
// accumulator, strict ascending adds == numpy's dense k-sequential FMA chain
// (fma(1,w,a)=a+w exactly; fma(0,w,a)=a exactly) — the R6..R12-validated order.
// One straight-line asm block per 32-slot chunk: 4 sub-batches of 8 loads,
// 2 sub-batches in flight, counted vmcnt waits. No branches; loaded values
// never cross an asm boundary while in flight.

#define DS8 \
  "ds_read_b32 %[a0], %[vL]\n\t"           \
  "ds_read_b32 %[a1], %[vL] offset:4\n\t"  \
  "ds_read_b32 %[a2], %[vL] offset:8\n\t"  \
  "ds_read_b32 %[a3], %[vL] offset:12\n\t" \
  "ds_read_b32 %[a4], %[vL] offset:16\n\t" \
  "ds_read_b32 %[a5], %[vL] offset:20\n\t" \
  "ds_read_b32 %[a6], %[vL] offset:24\n\t" \
  "ds_read_b32 %[a7], %[vL] offset:28\n\t" \
  "v_add_u32 %[vL], 32, %[vL]\n\t"

#define LD8(P, SHSTR) \
  "s_waitcnt lgkmcnt(0)\n\t" \
  "v_lshl_add_u32 %[a0], %[a0], " SHSTR ", %[vi]\n\t" \
  "v_lshl_add_u32 %[a1], %[a1], " SHSTR ", %[vi]\n\t" \
  "v_lshl_add_u32 %[a2], %[a2], " SHSTR ", %[vi]\n\t" \
  "v_lshl_add_u32 %[a3], %[a3], " SHSTR ", %[vi]\n\t" \
  "v_lshl_add_u32 %[a4], %[a4], " SHSTR ", %[vi]\n\t" \
  "v_lshl_add_u32 %[a5], %[a5], " SHSTR ", %[vi]\n\t" \
  "v_lshl_add_u32 %[a6], %[a6], " SHSTR ", %[vi]\n\t" \
  "v_lshl_add_u32 %[a7], %[a7], " SHSTR ", %[vi]\n\t" \
  "global_load_dword %[" #P "0], %[a0], %[wb]\n\t" \
  "global_load_dword %[" #P "1], %[a1], %[wb]\n\t" \
  "global_load_dword %[" #P "2], %[a2], %[wb]\n\t" \
  "global_load_dword %[" #P "3], %[a3], %[wb]\n\t" \
  "global_load_dword %[" #P "4], %[a4], %[wb]\n\t" \
  "global_load_dword %[" #P "5], %[a5], %[wb]\n\t" \
  "global_load_dword %[" #P "6], %[a6], %[wb]\n\t" \
  "global_load_dword %[" #P "7], %[a7], %[wb]\n\t"

#define ADD8(P) \
  "v_add_f32 %[ac], %[ac], %[" #P "0]\n\t" \
  "v_add_f32 %[ac], %[ac], %[" #P "1]\n\t" \
  "v_add_f32 %[ac], %[ac], %[" #P "2]\n\t" \
  "v_add_f32 %[ac], %[ac], %[" #P "3]\n\t" \
  "v_add_f32 %[ac], %[ac], %[" #P "4]\n\t" \
  "v_add_f32 %[ac], %[ac], %[" #P "5]\n\t" \
  "v_add_f32 %[ac], %[ac], %[" #P "6]\n\t" \
  "v_add_f32 %[ac], %[ac], %[" #P "7]\n\t"

#define DEF_WALK(NAME, SHSTR)                                              \
__device__ __forceinline__ float NAME(const int* lidx, int n,              \
                                      const float* wbase, int i4) {        \
  float acc = 0.0f;                                                        \
  int nc = (n + 31) >> 5;                                                  \
  unsigned vL = (unsigned)(unsigned long long)lidx;  /* low32 = LDS off */ \
  for (int c = 0; c < nc; ++c) {                                           \
    float a0,a1,a2,a3,a4,a5,a6,a7;                                         \
    float d0,d1,d2,d3,d4,d5,d6,d7;                                         \
    float e0,e1,e2,e3,e4,e5,e6,e7;                                         \
    asm volatile(                                                          \
      DS8                      /* sb0 idx */                               \
      LD8(d, SHSTR)            /* sb0 -> d (8 in flight) */                \
      DS8                      /* sb1 idx */                               \
      LD8(e, SHSTR)            /* sb1 -> e (16) */                         \
      DS8                      /* sb2 idx prefetch */                      \
      "s_waitcnt vmcnt(8)\n\t" /* sb0 done */                              \
      ADD8(d)                                                              \
      LD8(d, SHSTR)            /* sb2 -> d (16) */                         \
      DS8                      /* sb3 idx prefetch */                      \
      "s_waitcnt vmcnt(8)\n\t" /* sb1 done */                              \
      ADD8(e)                                                              \
      LD8(e, SHSTR)            /* sb3 -> e (16) */                         \
      "s_waitcnt vmcnt(8)\n\t" /* sb2 done */                              \
      ADD8(d)                                                              \
      "s_waitcnt vmcnt(0)\n\t" /* sb3 done */                              \
      ADD8(e)                                                              \
      : [a0]"=&v"(a0), [a1]"=&v"(a1), [a2]"=&v"(a2), [a3]"=&v"(a3),        \
        [a4]"=&v"(a4), [a5]"=&v"(a5), [a6]"=&v"(a6), [a7]"=&v"(a7),        \
        [d0]"=&v"(d0), [d1]"=&v"(d1), [d2]"=&v"(d2), [d3]"=&v"(d3),        \
        [d4]"=&v"(d4), [d5]"=&v"(d5), [d6]"=&v"(d6), [d7]"=&v"(d7),        \
        [e0]"=&v"(e0), [e1]"=&v"(e1), [e2]"=&v"(e2), [e3]"=&v"(e3),        \
        [e4]"=&v"(e4), [e5]"=&v"(e5), [e6]"=&v"(e6), [e7]"=&v"(e7),        \
        [ac]"+v"(acc), [vL]"+v"(vL)                                        \
      : [vi]"v"(i4), [wb]"s"(wbase)                                        \
      : "memory");                                                         \
  }                                                                        \
  return acc;                                                              \
}

DEF_WALK(walk_sh10, "10")   // rows of 256 floats (1024 B)
DEF_WALK(walk_sh8,  "8")    // rows of 64 floats (256 B, WoutT)

// ---------- R11-validated fallback walk (tiny-ws path only) ----------
__device__ __forceinline__ float walk16(const unsigned long long* __restrict__ m4,
                                        const float* __restrict__ base,
                                        int sjj, int sii, int i) {
  float a = 0.f;
#pragma unroll
  for (int w = 0; w < 4; ++w) {
    unsigned long long m = m4[w];
    const float* bp = base + (size_t)(w * 64) * sjj + (size_t)i * sii;
    while (m) {
      float t0,t1,t2,t3,t4,t5,t6,t7,t8,t9,t10,t11,t12,t13,t14,t15;
#define GRAB(tk) { int j = m ? (__ffsll(m) - 1) : 0;            \
                   float v = bp[(size_t)j * sjj];               \
                   tk = m ? v : 0.0f;                           \
                   m &= m - 1; }
      GRAB(t0)  GRAB(t1)  GRAB(t2)  GRAB(t3)
      GRAB(t4)  GRAB(t5)  GRAB(t6)  GRAB(t7)
      GRAB(t8)  GRAB(t9)  GRAB(t10) GRAB(t11)
      GRAB(t12) GRAB(t13) GRAB(t14) GRAB(t15)
#undef GRAB
      a += t0;  a += t1;  a += t2;  a += t3;
      a += t4;  a += t5;  a += t6;  a += t7;
      a += t8;  a += t9;  a += t10; a += t11;
      a += t12; a += t13; a += t14; a += t15;
    }
  }
  return a;
}

// ---------- pre 1 (R8-validated): xw[b][t][i] = sum_k x[b,t,k]*W_in[i,k] ----------
__launch_bounds__(256)
__global__ void srnn_xw(const float* __restrict__ x,
                        const float* __restrict__ Win,
                        float* __restrict__ xw) {
  __shared__ float win[N_IN * H];
  __shared__ float xt[32][N_IN];
  const int tid = (int)threadIdx.x;
  const int b  = (int)blockIdx.x >> 5;
  const int t0 = ((int)blockIdx.x & 31) * 32;
  for (int q = tid; q < H * N_IN; q += 256) {
    int i2 = q >> 7, k = q & (N_IN - 1);
    win[k * H + i2] = Win[q];
  }
  for (int q = tid; q < 32 * N_IN; q += 256) {
    int r = q >> 7, k = q & (N_IN - 1);
    xt[r][k] = x[((size_t)b * T_STEPS + t0 + r) * N_IN + k];
  }
  __syncthreads();
  const int i = tid;
  for (int r = 0; r < 32; r += 4) {
    float a0 = 0.f, a1 = 0.f, a2 = 0.f, a3 = 0.f;
#pragma unroll 16
    for (int k = 0; k < N_IN; ++k) {
      float wv = win[k * H + i];
      a0 = fmaf(xt[r + 0][k], wv, a0);
      a1 = fmaf(xt[r + 1][k], wv, a1);
      a2 = fmaf(xt[r + 2][k], wv, a2);
      a3 = fmaf(xt[r + 3][k], wv, a3);
    }
    xw[((size_t)b * T_STEPS + t0 + r + 0) * H + i] = a0;
    xw[((size_t)b * T_STEPS + t0 + r + 1) * H + i] = a1;
    xw[((size_t)b * T_STEPS + t0 + r + 2) * H + i] = a2;
    xw[((size_t)b * T_STEPS + t0 + r + 3) * H + i] = a3;
  }
}

// ---------- pre 2 (R10-validated): transpose weights with a 257th ZERO row ----
// ws floats: Wh1T @0 (257*256) | W12T @65792 | Wh2T @131584 | WoutT @197376 (257*64)
__global__ void srnn_prep(const float* __restrict__ Wh1,
                          const float* __restrict__ W12,
                          const float* __restrict__ Wh2,
                          const float* __restrict__ Wout,
                          float* __restrict__ ws) {
  int idx = blockIdx.x * 256 + (int)threadIdx.x;
  if (idx >= 3 * 65792 + 16448) return;
  if (idx < 3 * 65792) {
    int mat = idx / 65792;
    int rem = idx - mat * 65792;
    int j = rem >> 8, i = rem & 255;
    const float* src = (mat == 0) ? Wh1 : (mat == 1) ? W12 : Wh2;
    ws[idx] = (j < H) ? src[i * H + j] : 0.0f;
  } else {
    int rem = idx - 3 * 65792;
    int j = rem >> 6, o = rem & 63;
    ws[idx] = (j < H) ? Wout[o * H + j] : 0.0f;
  }
}

// ---------- main scan: L (4 concurrent walks) / M (membranes) / C (compaction) --
#define BUILD_LISTS()                                                           \
  if (tid < 512) {                                                              \
    const bool l1 = tid < 256;                                                  \
    const int  tt = tid & 255;                                                  \
    const int  w  = tt >> 6, l = tt & 63;                                       \
    unsigned long long mw = l1 ? s1m[w] : s2m[w];                               \
    const int* cp = l1 ? cnt1 : cnt2;                                           \
    int* lst = l1 ? idxL1 : idxL2;                                              \
    int base = (w > 0 ? cp[0] : 0) + (w > 1 ? cp[1] : 0) + (w > 2 ? cp[2] : 0); \
    int rank = base + (int)__popcll(mw & ((1ull << l) - 1ull));                 \
    if ((mw >> l) & 1ull) lst[rank] = tt;                                       \
    if (tt < 32) {                                                              \
      int ntot = cp[0] + cp[1] + cp[2] + cp[3];                                 \
      lst[ntot + tt] = 256;                                                     \
      if (tt == 0) { if (l1) n1s = ntot; else n2s = ntot; }                     \
    }                                                                           \
  }

template<int MODE>   // 0: xw precomputed; 1: in-scan x-dot via win_lds
__launch_bounds__(1024)
__global__ void srnn_scan4(const float* __restrict__ x,
                           const float* __restrict__ xw,
                           const float* __restrict__ Win,
                           const float* __restrict__ bin_p, const float* __restrict__ bh1_p,
                           const float* __restrict__ b12_p, const float* __restrict__ bh2_p,
                           const float* __restrict__ Wh1b,
                           const float* __restrict__ W12b,
                           const float* __restrict__ Wh2b,
                           const float* __restrict__ Wob,
                           const float* __restrict__ bo_p,
                           float* __restrict__ out) {
  __shared__ float h1d[H], h2d[H];
  __shared__ unsigned long long s1m[4], s2m[4];
  __shared__ int cnt1[4], cnt2[4];
  __shared__ int idxL1[H + 32], idxL2[H + 32];
  __shared__ int n1s, n2s;
  __shared__ float win_lds[(MODE == 1) ? (N_IN * 257) : 1];
  __shared__ float xs[(MODE == 1) ? 2 : 1][N_IN];

  const int tid = (int)threadIdx.x;
  const int g   = tid >> 8;
  const int i   = tid & 255;
  const int bb  = (int)blockIdx.x;

  if (MODE == 1) {
    for (int q = tid; q < H * N_IN; q += 1024) {
      int i2 = q >> 7, k = q & (N_IN - 1);
      win_lds[k * 257 + i2] = Win[q];
    }
    if (tid < N_IN) xs[0][tid] = x[(size_t)bb * (T_STEPS * N_IN) + tid];
  }
  if (tid < 4) { s2m[tid] = 0ull; cnt2[tid] = 0; cnt1[tid] = 0; }

  const float bin_i = (tid < H) ? bin_p[i] : 0.f;
  const float bh1_i = (tid < H) ? bh1_p[i] : 0.f;
  const float b12_i = (tid < H) ? b12_p[i] : 0.f;
  const float bh2_i = (tid < H) ? bh2_p[i] : 0.f;
  const float bo_o  = (g == 3 && i < N_OUT) ? bo_p[i] : 0.f;

  float m1 = 0.f, m2 = 0.f, acc = 0.f, c12v = 0.f, xv_next = 0.f;

  __syncthreads();

  // ---- prologue: u1(0) (h1 term is exactly +0.0), ballot s1(0)
  if (tid < H) {
    float xv0;
    if (MODE == 0) {
      xv0     = xw[((size_t)bb * T_STEPS + 0) * H + i];
      xv_next = xw[((size_t)bb * T_STEPS + 1) * H + i];
    } else {
      float a = 0.f;
#pragma unroll 16
      for (int k = 0; k < N_IN; ++k)
        a = fmaf(xs[0][k], win_lds[k * 257 + i], a);
      xv0 = a;
    }
    float u1 = 0.9f * m1;
    u1 = u1 + xv0;
    u1 = u1 + bin_i;
    u1 = u1 + 0.0f;
    u1 = u1 + bh1_i;
    bool sp = (u1 - 1.0f) > 0.0f;
    m1 = u1 - (sp ? 1.0f : 0.0f);
    unsigned long long bm = __ballot(sp);
    if ((tid & 63) == 0) { s1m[tid >> 6] = bm; cnt1[tid >> 6] = (int)__popcll(bm); }
  }
  __syncthreads();
  BUILD_LISTS();
  __syncthreads();

  for (int t = 0; t < T_STEPS; ++t) {
    // ---- L(t): four concurrent walks over compact lists
    if (g == 0) {
      c12v = walk_sh10(idxL1, n1s, W12b, i * 4);             // s1(t) -> layer2
    } else if (g == 1) {
      h2d[i] = walk_sh10(idxL2, n2s, Wh2b, i * 4);           // s2(t-1)
    } else if (g == 2) {
      h1d[i] = walk_sh10(idxL1, n1s, Wh1b, i * 4);           // s1(t) -> u1(t+1)
    } else {
      if (i < N_OUT) {
        if (t > WARM) {                                      // readout of s2(t-1)
          float d = walk_sh8(idxL2, n2s, Wob, i * 4);
          acc = acc + (d + bo_o);
        }
      } else if (MODE == 1 && i >= 64 && i < 64 + N_IN && t + 1 < T_STEPS) {
        xs[(t & 1) ^ 1][i - 64] =
            x[(size_t)bb * (T_STEPS * N_IN) + (size_t)(t + 1) * N_IN + (i - 64)];
      }
    }
    __syncthreads();

    // ---- M(t): u2(t) then u1(t+1) (validated left-assoc chains)
    if (tid < H) {
      float u2 = 0.9f * m2;
      u2 = u2 + c12v;
      u2 = u2 + b12_i;
      u2 = u2 + h2d[i];
      u2 = u2 + bh2_i;
      bool sp2 = (u2 - 1.0f) > 0.0f;
      m2 = u2 - (sp2 ? 1.0f : 0.0f);
      unsigned long long bm2 = __ballot(sp2);
      if ((tid & 63) == 0) { s2m[tid >> 6] = bm2; cnt2[tid >> 6] = (int)__popcll(bm2); }

      if (t + 1 < T_STEPS) {
        float xv;
        if (MODE == 0) {
          xv = xv_next;
        } else {
          float a = 0.f;
#pragma unroll 16
          for (int k = 0; k < N_IN; ++k)
            a = fmaf(xs[(t & 1) ^ 1][k], win_lds[k * 257 + i], a);
          xv = a;
        }
        float u1 = 0.9f * m1;
        u1 = u1 + xv;
        u1 = u1 + bin_i;
        u1 = u1 + h1d[i];
        u1 = u1 + bh1_i;
        bool sp1 = (u1 - 1.0f) > 0.0f;
        m1 = u1 - (sp1 ? 1.0f : 0.0f);
        unsigned long long bm1 = __ballot(sp1);
        if ((tid & 63) == 0) { s1m[tid >> 6] = bm1; cnt1[tid >> 6] = (int)__popcll(bm1); }
        if (MODE == 0 && t + 2 < T_STEPS)
          xv_next = xw[((size_t)bb * T_STEPS + (t + 2)) * H + i];
      }
    }
    __syncthreads();

    // ---- C(t): rank-compaction of the fresh ballots into flat ascending lists
    BUILD_LISTS();
    __syncthreads();
  }

  // ---- epilogue: readout of s2(1023) (idxL2 built in C(1023))
  if (g == 3 && i < N_OUT) {
    float d = walk_sh8(idxL2, n2s, Wob, i * 4);
    acc = acc + (d + bo_o);
    out[(size_t)bb * N_OUT + i] = acc / 1014.0f;
  }
}

// ---------- R11-validated fallback scan (tiny-ws path, original layouts) ----------
__launch_bounds__(1024)
__global__ void srnn_scan3f(const float* __restrict__ x,
                            const float* __restrict__ Win,
                            const float* __restrict__ bin_p, const float* __restrict__ bh1_p,
                            const float* __restrict__ b12_p, const float* __restrict__ bh2_p,
                            const float* __restrict__ Wh1b, int h1j, int h1i,
                            const float* __restrict__ W12b, int c12j, int c12i,
                            const float* __restrict__ Wh2b, int h2j, int h2i,
                            const float* __restrict__ Wob,  int woj, int woi,
                            const float* __restrict__ bo_p,
                            float* __restrict__ out) {
  __shared__ float h1d[H], h2d[H];
  __shared__ unsigned long long s1m[2][4], s2m[2][4];
  __shared__ float win_lds[N_IN * 257];
  __shared__ float xs[2][N_IN];

  const int tid = (int)threadIdx.x;
  const int g   = tid >> 8;
  const int i   = tid & 255;
  const int b   = (int)blockIdx.x;

  for (int q = tid; q < H * N_IN; q += 1024) {
    int i2 = q >> 7, k = q & (N_IN - 1);
    win_lds[k * 257 + i2] = Win[q];
  }
  if (tid < N_IN) xs[0][tid] = x[(size_t)b * (T_STEPS * N_IN) + tid];
  if (tid < 4)       { s1m[0][tid] = 0ull; s2m[0][tid] = 0ull; }
  else if (tid < 8)  { s1m[1][tid - 4] = 0ull; s2m[1][tid - 4] = 0ull; }

  const float bin_i = (tid < H) ? bin_p[i] : 0.f;
  const float bh1_i = (tid < H) ? bh1_p[i] : 0.f;
  const float b12_i = (tid < H) ? b12_p[i] : 0.f;
  const float bh2_i = (tid < H) ? bh2_p[i] : 0.f;
  const float bo_o  = (g == 3 && i < N_OUT) ? bo_p[i] : 0.f;

  float m1 = 0.f, m2 = 0.f, acc = 0.f, c12v = 0.f;

  __syncthreads();

  if (tid < H) {
    float a = 0.f;
#pragma unroll 16
    for (int k = 0; k < N_IN; ++k)
      a = fmaf(xs[0][k], win_lds[k * 257 + i], a);
    float u1 = 0.9f * m1;
    u1 = u1 + a;
    u1 = u1 + bin_i;
    u1 = u1 + 0.0f;
    u1 = u1 + bh1_i;
    bool sp = (u1 - 1.0f) > 0.0f;
    m1 = u1 - (sp ? 1.0f : 0.0f);
    unsigned long long bm = __ballot(sp);
    if ((tid & 63) == 0) s1m[0][tid >> 6] = bm;
  }
  __syncthreads();

  for (int t = 0; t < T_STEPS; ++t) {
    const int cb = t & 1;
    const int pb = cb ^ 1;
    if (g == 0) {
      c12v = walk16(s1m[cb], W12b, c12j, c12i, i);
    } else if (g == 1) {
      h2d[i] = walk16(s2m[pb], Wh2b, h2j, h2i, i);
    } else if (g == 2) {
      h1d[i] = walk16(s1m[cb], Wh1b, h1j, h1i, i);
    } else {
      if (i < N_OUT) {
        if (t > WARM) {
          float d = walk16(s2m[pb], Wob, woj, woi, i);
          acc = acc + (d + bo_o);
        }
      } else if (i >= 64 && i < 64 + N_IN && t + 1 < T_STEPS) {
        xs[pb][i - 64] = x[(size_t)b * (T_STEPS * N_IN) + (size_t)(t + 1) * N_IN + (i - 64)];
      }
    }
    __syncthreads();
    if (tid < H) {
      float u2 = 0.9f * m2;
      u2 = u2 + c12v;
      u2 = u2 + b12_i;
      u2 = u2 + h2d[i];
      u2 = u2 + bh2_i;
      bool sp2 = (u2 - 1.0f) > 0.0f;
      m2 = u2 - (sp2 ? 1.0f : 0.0f);
      unsigned long long bm2 = __ballot(sp2);
      if ((tid & 63) == 0) s2m[cb][tid >> 6] = bm2;
      if (t + 1 < T_STEPS) {
        float a = 0.f;
#pragma unroll 16
        for (int k = 0; k < N_IN; ++k)
          a = fmaf(xs[pb][k], win_lds[k * 257 + i], a);
        float u1 = 0.9f * m1;
        u1 = u1 + a;
        u1 = u1 + bin_i;
        u1 = u1 + h1d[i];
        u1 = u1 + bh1_i;
        bool sp1 = (u1 - 1.0f) > 0.0f;
        m1 = u1 - (sp1 ? 1.0f : 0.0f);
        unsigned long long bm1 = __ballot(sp1);
        if ((tid & 63) == 0) s1m[pb][tid >> 6] = bm1;
      }
    }
    __syncthreads();
  }

  if (g == 3 && i < N_OUT) {
    float d = walk16(s2m[1], Wob, woj, woi, i);
    acc = acc + (d + bo_o);
    out[(size_t)b * N_OUT + i] = acc / 1014.0f;
  }
}

// ---------- launch ----------
extern "C" void kernel_launch(void* const* d_in, const int* in_sizes, int n_in,
                              void* d_out, int out_size, void* d_ws, size_t ws_size,
                              hipStream_t stream) {
  const float* x     = (const float*)d_in[0];
  const float* W_in  = (const float*)d_in[1];
  const float* b_in  = (const float*)d_in[2];
  const float* W_h1  = (const float*)d_in[3];
  const float* b_h1  = (const float*)d_in[4];
  const float* W_12  = (const float*)d_in[5];
  const float* b_12  = (const float*)d_in[6];
  const float* W_h2  = (const float*)d_in[7];
  const float* b_h2  = (const float*)d_in[8];
  const float* W_out = (const float*)d_in[9];
  const float* b_out = (const float*)d_in[10];
  float* out = (float*)d_out;
  float* wsf = (float*)d_ws;

  const size_t XW_FLOATS = (size_t)256 * T_STEPS * H;        // 67,108,864
  const size_t TR_FLOATS = (size_t)3 * 65792 + 16448;        // 213,824 (zero rows)
  const size_t need0 = (XW_FLOATS + TR_FLOATS) * sizeof(float);
  const size_t need1 = TR_FLOATS * sizeof(float);

  if (ws_size >= need0) {
    float* xwp = wsf;
    float* tr  = wsf + XW_FLOATS;
    srnn_xw<<<8192, 256, 0, stream>>>(x, W_in, xwp);
    srnn_prep<<<(int)((TR_FLOATS + 255) / 256), 256, 0, stream>>>(W_h1, W_12, W_h2, W_out, tr);
    srnn_scan4<0><<<256, 1024, 0, stream>>>(
        x, xwp, W_in, b_in, b_h1, b_12, b_h2,
        tr, tr + 65792, tr + 131584, tr + 197376, b_out, out);
  } else if (ws_size >= need1) {
    float* tr = wsf;
    srnn_prep<<<(int)((TR_FLOATS + 255) / 256), 256, 0, stream>>>(W_h1, W_12, W_h2, W_out, tr);
    srnn_scan4<1><<<256, 1024, 0, stream>>>(
        x, nullptr, W_in, b_in, b_h1, b_12, b_h2,
        tr, tr + 65792, tr + 131584, tr + 197376, b_out, out);
  } else {
    srnn_scan3f<<<256, 1024, 0, stream>>>(
        x, W_in, b_in, b_h1, b_12, b_h2,
        W_h1,  1, H,
        W_12,  1, H,
        W_h2,  1, H,
        W_out, 1, H,
        b_out, out);
  }
}

// Round 15
// 2394.076 us; speedup vs baseline: 2.7811x; 1.2929x over previous
//
#include <hip/hip_runtime.h>

#define T_STEPS 1024
#define N_IN    128
#define H       256
#define N_OUT   64
#define WARM    10

// ===================== R13-validated asm walk =====================
// Index list holds spiking-neuron indices in ASCENDING order, padded to a
// multiple of 32 with index 256 -> a zero row appended to each transposed
// weight matrix (adds +0.0f, an exact identity). Single accumulator, strict
// ascending adds == numpy's dense k-sequential chain. One straight-line asm
// block per 32-slot chunk: 4 sub-batches of 8 loads, 2 in flight, counted
// vmcnt waits. Loads NEVER cross an asm boundary while in flight.

#define DS8 \
  "ds_read_b32 %[a0], %[vL]\n\t"           \
  "ds_read_b32 %[a1], %[vL] offset:4\n\t"  \
  "ds_read_b32 %[a2], %[vL] offset:8\n\t"  \
  "ds_read_b32 %[a3], %[vL] offset:12\n\t" \
  "ds_read_b32 %[a4], %[vL] offset:16\n\t" \
  "ds_read_b32 %[a5], %[vL] offset:20\n\t" \
  "ds_read_b32 %[a6], %[vL] offset:24\n\t" \
  "ds_read_b32 %[a7], %[vL] offset:28\n\t" \
  "v_add_u32 %[vL], 32, %[vL]\n\t"

#define LD8(P, SHSTR) \
  "s_waitcnt lgkmcnt(0)\n\t" \
  "v_lshl_add_u32 %[a0], %[a0], " SHSTR ", %[vi]\n\t" \
  "v_lshl_add_u32 %[a1], %[a1], " SHSTR ", %[vi]\n\t" \
  "v_lshl_add_u32 %[a2], %[a2], " SHSTR ", %[vi]\n\t" \
  "v_lshl_add_u32 %[a3], %[a3], " SHSTR ", %[vi]\n\t" \
  "v_lshl_add_u32 %[a4], %[a4], " SHSTR ", %[vi]\n\t" \
  "v_lshl_add_u32 %[a5], %[a5], " SHSTR ", %[vi]\n\t" \
  "v_lshl_add_u32 %[a6], %[a6], " SHSTR ", %[vi]\n\t" \
  "v_lshl_add_u32 %[a7], %[a7], " SHSTR ", %[vi]\n\t" \
  "global_load_dword %[" #P "0], %[a0], %[wb]\n\t" \
  "global_load_dword %[" #P "1], %[a1], %[wb]\n\t" \
  "global_load_dword %[" #P "2], %[a2], %[wb]\n\t" \
  "global_load_dword %[" #P "3], %[a3], %[wb]\n\t" \
  "global_load_dword %[" #P "4], %[a4], %[wb]\n\t" \
  "global_load_dword %[" #P "5], %[a5], %[wb]\n\t" \
  "global_load_dword %[" #P "6], %[a6], %[wb]\n\t" \
  "global_load_dword %[" #P "7], %[a7], %[wb]\n\t"

#define ADD8(P) \
  "v_add_f32 %[ac], %[ac], %[" #P "0]\n\t" \
  "v_add_f32 %[ac], %[ac], %[" #P "1]\n\t" \
  "v_add_f32 %[ac], %[ac], %[" #P "2]\n\t" \
  "v_add_f32 %[ac], %[ac], %[" #P "3]\n\t" \
  "v_add_f32 %[ac], %[ac], %[" #P "4]\n\t" \
  "v_add_f32 %[ac], %[ac], %[" #P "5]\n\t" \
  "v_add_f32 %[ac], %[ac], %[" #P "6]\n\t" \
  "v_add_f32 %[ac], %[ac], %[" #P "7]\n\t"

#define DEF_WALK(NAME, SHSTR)                                              \
__device__ __forceinline__ float NAME(const int* lidx, int n,              \
                                      const float* wbase, int i4) {        \
  float acc = 0.0f;                                                        \
  int nc = (n + 31) >> 5;                                                  \
  unsigned vL = (unsigned)(unsigned long long)lidx;  /* low32 = LDS off */ \
  for (int c = 0; c < nc; ++c) {                                           \
    float a0,a1,a2,a3,a4,a5,a6,a7;                                         \
    float d0,d1,d2,d3,d4,d5,d6,d7;                                         \
    float e0,e1,e2,e3,e4,e5,e6,e7;                                         \
    asm volatile(                                                          \
      DS8                      /* sb0 idx */                               \
      LD8(d, SHSTR)            /* sb0 -> d (8 in flight) */                \
      DS8                      /* sb1 idx */                               \
      LD8(e, SHSTR)            /* sb1 -> e (16) */                         \
      DS8                      /* sb2 idx prefetch */                      \
      "s_waitcnt vmcnt(8)\n\t" /* sb0 done */                              \
      ADD8(d)                                                              \
      LD8(d, SHSTR)            /* sb2 -> d (16) */                         \
      DS8                      /* sb3 idx prefetch */                      \
      "s_waitcnt vmcnt(8)\n\t" /* sb1 done */                              \
      ADD8(e)                                                              \
      LD8(e, SHSTR)            /* sb3 -> e (16) */                         \
      "s_waitcnt vmcnt(8)\n\t" /* sb2 done */                              \
      ADD8(d)                                                              \
      "s_waitcnt vmcnt(0)\n\t" /* sb3 done */                              \
      ADD8(e)                                                              \
      : [a0]"=&v"(a0), [a1]"=&v"(a1), [a2]"=&v"(a2), [a3]"=&v"(a3),        \
        [a4]"=&v"(a4), [a5]"=&v"(a5), [a6]"=&v"(a6), [a7]"=&v"(a7),        \
        [d0]"=&v"(d0), [d1]"=&v"(d1), [d2]"=&v"(d2), [d3]"=&v"(d3),        \
        [d4]"=&v"(d4), [d5]"=&v"(d5), [d6]"=&v"(d6), [d7]"=&v"(d7),        \
        [e0]"=&v"(e0), [e1]"=&v"(e1), [e2]"=&v"(e2), [e3]"=&v"(e3),        \
        [e4]"=&v"(e4), [e5]"=&v"(e5), [e6]"=&v"(e6), [e7]"=&v"(e7),        \
        [ac]"+v"(acc), [vL]"+v"(vL)                                        \
      : [vi]"v"(i4), [wb]"s"(wbase)                                        \
      : "memory");                                                         \
  }                                                                        \
  return acc;                                                              \
}

DEF_WALK(walk_sh10, "10")   // rows of 256 floats (1024 B)
DEF_WALK(walk_sh8,  "8")    // rows of 64 floats (256 B, WoutT)

// ---------- R11-validated fallback walk (tiny-ws path only) ----------
__device__ __forceinline__ float walk16(const unsigned long long* __restrict__ m4,
                                        const float* __restrict__ base,
                                        int sjj, int sii, int i) {
  float a = 0.f;
#pragma unroll
  for (int w = 0; w < 4; ++w) {
    unsigned long long m = m4[w];
    const float* bp = base + (size_t)(w * 64) * sjj + (size_t)i * sii;
    while (m) {
      float t0,t1,t2,t3,t4,t5,t6,t7,t8,t9,t10,t11,t12,t13,t14,t15;
#define GRAB(tk) { int j = m ? (__ffsll(m) - 1) : 0;            \
                   float v = bp[(size_t)j * sjj];               \
                   tk = m ? v : 0.0f;                           \
                   m &= m - 1; }
      GRAB(t0)  GRAB(t1)  GRAB(t2)  GRAB(t3)
      GRAB(t4)  GRAB(t5)  GRAB(t6)  GRAB(t7)
      GRAB(t8)  GRAB(t9)  GRAB(t10) GRAB(t11)
      GRAB(t12) GRAB(t13) GRAB(t14) GRAB(t15)
#undef GRAB
      a += t0;  a += t1;  a += t2;  a += t3;
      a += t4;  a += t5;  a += t6;  a += t7;
      a += t8;  a += t9;  a += t10; a += t11;
      a += t12; a += t13; a += t14; a += t15;
    }
  }
  return a;
}

// ---------- prep: transposed weights (+ zero rows) + WinT ----------
// ws floats (relative to tr base):
//   Wh1T @0 (257*256) | W12T @65792 | Wh2T @131584 | WoutT @197376 (257*64)
//   WinT @213824 (128 rows of 256: WinT[k][i] = W_in[i][k])   total 246592
#define WOUT_OFF 197376
#define WINT_OFF 213824
#define TRTOT    246592
__global__ void srnn_prep(const float* __restrict__ Win,
                          const float* __restrict__ Wh1,
                          const float* __restrict__ W12,
                          const float* __restrict__ Wh2,
                          const float* __restrict__ Wout,
                          float* __restrict__ ws) {
  int idx = blockIdx.x * 256 + (int)threadIdx.x;
  if (idx >= TRTOT) return;
  if (idx < 3 * 65792) {
    int mat = idx / 65792;
    int rem = idx - mat * 65792;
    int j = rem >> 8, i = rem & 255;
    const float* src = (mat == 0) ? Wh1 : (mat == 1) ? W12 : Wh2;
    ws[idx] = (j < H) ? src[i * H + j] : 0.0f;
  } else if (idx < WINT_OFF) {
    int rem = idx - WOUT_OFF;
    int j = rem >> 6, o = rem & 63;
    ws[idx] = (j < H) ? Wout[o * H + j] : 0.0f;
  } else {
    int rem = idx - WINT_OFF;
    int k = rem >> 8, i = rem & 255;
    ws[idx] = Win[i * N_IN + k];                  // WinT[k][i]
  }
}

// ---------- xw precompute, occupancy-fixed: 16KB LDS, many blocks/CU ----------
// Chain per (row,i): single accumulator, k ascending, fmaf — bit-identical
// to the validated in-scan chain.
__launch_bounds__(256)
__global__ void srnn_xw2(const float* __restrict__ x,
                         const float* __restrict__ WinT,
                         float* __restrict__ xw) {
  __shared__ float xt[32][N_IN];                  // 16 KB
  const int tid = (int)threadIdx.x;
  const int b  = (int)blockIdx.x >> 5;
  const int t0 = ((int)blockIdx.x & 31) * 32;
  {
    const float4* src = reinterpret_cast<const float4*>(
        x + ((size_t)b * T_STEPS + t0) * N_IN);
    float4* dst = reinterpret_cast<float4*>(&xt[0][0]);
    for (int q = tid; q < 32 * N_IN / 4; q += 256) dst[q] = src[q];
  }
  __syncthreads();
  const int i = tid;
  float a[32];
#pragma unroll
  for (int r = 0; r < 32; ++r) a[r] = 0.f;
#pragma unroll 4
  for (int k = 0; k < N_IN; ++k) {
    float w = WinT[k * H + i];                    // coalesced, L2-hot
#pragma unroll
    for (int r = 0; r < 32; ++r) a[r] = fmaf(xt[r][k], w, a[r]);
  }
  float* dst = xw + ((size_t)b * T_STEPS + t0) * H + i;
#pragma unroll
  for (int r = 0; r < 32; ++r) dst[(size_t)r * H] = a[r];
}

// ---------- main scan (R13-validated): L (4 walks) / M / C ----------
#define BUILD_LISTS()                                                           \
  if (tid < 512) {                                                              \
    const bool l1 = tid < 256;                                                  \
    const int  tt = tid & 255;                                                  \
    const int  w  = tt >> 6, l = tt & 63;                                       \
    unsigned long long mw = l1 ? s1m[w] : s2m[w];                               \
    const int* cp = l1 ? cnt1 : cnt2;                                           \
    int* lst = l1 ? idxL1 : idxL2;                                              \
    int base = (w > 0 ? cp[0] : 0) + (w > 1 ? cp[1] : 0) + (w > 2 ? cp[2] : 0); \
    int rank = base + (int)__popcll(mw & ((1ull << l) - 1ull));                 \
    if ((mw >> l) & 1ull) lst[rank] = tt;                                       \
    if (tt < 32) {                                                              \
      int ntot = cp[0] + cp[1] + cp[2] + cp[3];                                 \
      lst[ntot + tt] = 256;                                                     \
      if (tt == 0) { if (l1) n1s = ntot; else n2s = ntot; }                     \
    }                                                                           \
  }

template<int MODE>   // 0: xw precomputed; 1: in-scan x-dot via win_lds
__launch_bounds__(1024)
__global__ void srnn_scan4(const float* __restrict__ x,
                           const float* __restrict__ xw,
                           const float* __restrict__ Win,
                           const float* __restrict__ bin_p, const float* __restrict__ bh1_p,
                           const float* __restrict__ b12_p, const float* __restrict__ bh2_p,
                           const float* __restrict__ Wh1b,
                           const float* __restrict__ W12b,
                           const float* __restrict__ Wh2b,
                           const float* __restrict__ Wob,
                           const float* __restrict__ bo_p,
                           float* __restrict__ out) {
  __shared__ float h1d[H], h2d[H];
  __shared__ unsigned long long s1m[4], s2m[4];
  __shared__ int cnt1[4], cnt2[4];
  __shared__ int idxL1[H + 32], idxL2[H + 32];
  __shared__ int n1s, n2s;
  __shared__ float win_lds[(MODE == 1) ? (N_IN * 257) : 1];
  __shared__ float xs[(MODE == 1) ? 2 : 1][N_IN];

  const int tid = (int)threadIdx.x;
  const int g   = tid >> 8;
  const int i   = tid & 255;
  const int bb  = (int)blockIdx.x;

  if (MODE == 1) {
    for (int q = tid; q < H * N_IN; q += 1024) {
      int i2 = q >> 7, k = q & (N_IN - 1);
      win_lds[k * 257 + i2] = Win[q];
    }
    if (tid < N_IN) xs[0][tid] = x[(size_t)bb * (T_STEPS * N_IN) + tid];
  }
  if (tid < 4) { s2m[tid] = 0ull; cnt2[tid] = 0; cnt1[tid] = 0; }

  const float bin_i = (tid < H) ? bin_p[i] : 0.f;
  const float bh1_i = (tid < H) ? bh1_p[i] : 0.f;
  const float b12_i = (tid < H) ? b12_p[i] : 0.f;
  const float bh2_i = (tid < H) ? bh2_p[i] : 0.f;
  const float bo_o  = (g == 3 && i < N_OUT) ? bo_p[i] : 0.f;

  float m1 = 0.f, m2 = 0.f, acc = 0.f, c12v = 0.f, xv_next = 0.f;

  __syncthreads();

  // ---- prologue: u1(0) (h1 term is exactly +0.0), ballot s1(0)
  if (tid < H) {
    float xv0;
    if (MODE == 0) {
      xv0     = xw[((size_t)bb * T_STEPS + 0) * H + i];
      xv_next = xw[((size_t)bb * T_STEPS + 1) * H + i];
    } else {
      float a = 0.f;
#pragma unroll 16
      for (int k = 0; k < N_IN; ++k)
        a = fmaf(xs[0][k], win_lds[k * 257 + i], a);
      xv0 = a;
    }
    float u1 = 0.9f * m1;
    u1 = u1 + xv0;
    u1 = u1 + bin_i;
    u1 = u1 + 0.0f;
    u1 = u1 + bh1_i;
    bool sp = (u1 - 1.0f) > 0.0f;
    m1 = u1 - (sp ? 1.0f : 0.0f);
    unsigned long long bm = __ballot(sp);
    if ((tid & 63) == 0) { s1m[tid >> 6] = bm; cnt1[tid >> 6] = (int)__popcll(bm); }
  }
  __syncthreads();
  BUILD_LISTS();
  __syncthreads();

  for (int t = 0; t < T_STEPS; ++t) {
    // ---- L(t): four concurrent walks over compact lists
    if (g == 0) {
      c12v = walk_sh10(idxL1, n1s, W12b, i * 4);             // s1(t) -> layer2
    } else if (g == 1) {
      h2d[i] = walk_sh10(idxL2, n2s, Wh2b, i * 4);           // s2(t-1)
    } else if (g == 2) {
      h1d[i] = walk_sh10(idxL1, n1s, Wh1b, i * 4);           // s1(t) -> u1(t+1)
    } else {
      if (i < N_OUT) {
        if (t > WARM) {                                      // readout of s2(t-1)
          float d = walk_sh8(idxL2, n2s, Wob, i * 4);
          acc = acc + (d + bo_o);
        }
      } else if (MODE == 1 && i >= 64 && i < 64 + N_IN && t + 1 < T_STEPS) {
        xs[(t & 1) ^ 1][i - 64] =
            x[(size_t)bb * (T_STEPS * N_IN) + (size_t)(t + 1) * N_IN + (i - 64)];
      }
    }
    __syncthreads();

    // ---- M(t): u2(t) then u1(t+1) (validated left-assoc chains)
    if (tid < H) {
      float u2 = 0.9f * m2;
      u2 = u2 + c12v;
      u2 = u2 + b12_i;
      u2 = u2 + h2d[i];
      u2 = u2 + bh2_i;
      bool sp2 = (u2 - 1.0f) > 0.0f;
      m2 = u2 - (sp2 ? 1.0f : 0.0f);
      unsigned long long bm2 = __ballot(sp2);
      if ((tid & 63) == 0) { s2m[tid >> 6] = bm2; cnt2[tid >> 6] = (int)__popcll(bm2); }

      if (t + 1 < T_STEPS) {
        float xv;
        if (MODE == 0) {
          xv = xv_next;
        } else {
          float a = 0.f;
#pragma unroll 16
          for (int k = 0; k < N_IN; ++k)
            a = fmaf(xs[(t & 1) ^ 1][k], win_lds[k * 257 + i], a);
          xv = a;
        }
        float u1 = 0.9f * m1;
        u1 = u1 + xv;
        u1 = u1 + bin_i;
        u1 = u1 + h1d[i];
        u1 = u1 + bh1_i;
        bool sp1 = (u1 - 1.0f) > 0.0f;
        m1 = u1 - (sp1 ? 1.0f : 0.0f);
        unsigned long long bm1 = __ballot(sp1);
        if ((tid & 63) == 0) { s1m[tid >> 6] = bm1; cnt1[tid >> 6] = (int)__popcll(bm1); }
        if (MODE == 0 && t + 2 < T_STEPS)
          xv_next = xw[((size_t)bb * T_STEPS + (t + 2)) * H + i];
      }
    }
    __syncthreads();

    // ---- C(t): rank-compaction of the fresh ballots into flat ascending lists
    BUILD_LISTS();
    __syncthreads();
  }

  // ---- epilogue: readout of s2(1023) (idxL2 built in C(1023))
  if (g == 3 && i < N_OUT) {
    float d = walk_sh8(idxL2, n2s, Wob, i * 4);
    acc = acc + (d + bo_o);
    out[(size_t)bb * N_OUT + i] = acc / 1014.0f;
  }
}

// ---------- R11-validated fallback scan (tiny-ws path, original layouts) ----------
__launch_bounds__(1024)
__global__ void srnn_scan3f(const float* __restrict__ x,
                            const float* __restrict__ Win,
                            const float* __restrict__ bin_p, const float* __restrict__ bh1_p,
                            const float* __restrict__ b12_p, const float* __restrict__ bh2_p,
                            const float* __restrict__ Wh1b, int h1j, int h1i,
                            const float* __restrict__ W12b, int c12j, int c12i,
                            const float* __restrict__ Wh2b, int h2j, int h2i,
                            const float* __restrict__ Wob,  int woj, int woi,
                            const float* __restrict__ bo_p,
                            float* __restrict__ out) {
  __shared__ float h1d[H], h2d[H];
  __shared__ unsigned long long s1m[2][4], s2m[2][4];
  __shared__ float win_lds[N_IN * 257];
  __shared__ float xs[2][N_IN];

  const int tid = (int)threadIdx.x;
  const int g   = tid >> 8;
  const int i   = tid & 255;
  const int b   = (int)blockIdx.x;

  for (int q = tid; q < H * N_IN; q += 1024) {
    int i2 = q >> 7, k = q & (N_IN - 1);
    win_lds[k * 257 + i2] = Win[q];
  }
  if (tid < N_IN) xs[0][tid] = x[(size_t)b * (T_STEPS * N_IN) + tid];
  if (tid < 4)       { s1m[0][tid] = 0ull; s2m[0][tid] = 0ull; }
  else if (tid < 8)  { s1m[1][tid - 4] = 0ull; s2m[1][tid - 4] = 0ull; }

  const float bin_i = (tid < H) ? bin_p[i] : 0.f;
  const float bh1_i = (tid < H) ? bh1_p[i] : 0.f;
  const float b12_i = (tid < H) ? b12_p[i] : 0.f;
  const float bh2_i = (tid < H) ? bh2_p[i] : 0.f;
  const float bo_o  = (g == 3 && i < N_OUT) ? bo_p[i] : 0.f;

  float m1 = 0.f, m2 = 0.f, acc = 0.f, c12v = 0.f;

  __syncthreads();

  if (tid < H) {
    float a = 0.f;
#pragma unroll 16
    for (int k = 0; k < N_IN; ++k)
      a = fmaf(xs[0][k], win_lds[k * 257 + i], a);
    float u1 = 0.9f * m1;
    u1 = u1 + a;
    u1 = u1 + bin_i;
    u1 = u1 + 0.0f;
    u1 = u1 + bh1_i;
    bool sp = (u1 - 1.0f) > 0.0f;
    m1 = u1 - (sp ? 1.0f : 0.0f);
    unsigned long long bm = __ballot(sp);
    if ((tid & 63) == 0) s1m[0][tid >> 6] = bm;
  }
  __syncthreads();

  for (int t = 0; t < T_STEPS; ++t) {
    const int cb = t & 1;
    const int pb = cb ^ 1;
    if (g == 0) {
      c12v = walk16(s1m[cb], W12b, c12j, c12i, i);
    } else if (g == 1) {
      h2d[i] = walk16(s2m[pb], Wh2b, h2j, h2i, i);
    } else if (g == 2) {
      h1d[i] = walk16(s1m[cb], Wh1b, h1j, h1i, i);
    } else {
      if (i < N_OUT) {
        if (t > WARM) {
          float d = walk16(s2m[pb], Wob, woj, woi, i);
          acc = acc + (d + bo_o);
        }
      } else if (i >= 64 && i < 64 + N_IN && t + 1 < T_STEPS) {
        xs[pb][i - 64] = x[(size_t)b * (T_STEPS * N_IN) + (size_t)(t + 1) * N_IN + (i - 64)];
      }
    }
    __syncthreads();
    if (tid < H) {
      float u2 = 0.9f * m2;
      u2 = u2 + c12v;
      u2 = u2 + b12_i;
      u2 = u2 + h2d[i];
      u2 = u2 + bh2_i;
      bool sp2 = (u2 - 1.0f) > 0.0f;
      m2 = u2 - (sp2 ? 1.0f : 0.0f);
      unsigned long long bm2 = __ballot(sp2);
      if ((tid & 63) == 0) s2m[cb][tid >> 6] = bm2;
      if (t + 1 < T_STEPS) {
        float a = 0.f;
#pragma unroll 16
        for (int k = 0; k < N_IN; ++k)
          a = fmaf(xs[pb][k], win_lds[k * 257 + i], a);
        float u1 = 0.9f * m1;
        u1 = u1 + a;
        u1 = u1 + bin_i;
        u1 = u1 + h1d[i];
        u1 = u1 + bh1_i;
        bool sp1 = (u1 - 1.0f) > 0.0f;
        m1 = u1 - (sp1 ? 1.0f : 0.0f);
        unsigned long long bm1 = __ballot(sp1);
        if ((tid & 63) == 0) s1m[pb][tid >> 6] = bm1;
      }
    }
    __syncthreads();
  }

  if (g == 3 && i < N_OUT) {
    float d = walk16(s2m[1], Wob, woj, woi, i);
    acc = acc + (d + bo_o);
    out[(size_t)b * N_OUT + i] = acc / 1014.0f;
  }
}

// ---------- launch ----------
extern "C" void kernel_launch(void* const* d_in, const int* in_sizes, int n_in,
                              void* d_out, int out_size, void* d_ws, size_t ws_size,
                              hipStream_t stream) {
  const float* x     = (const float*)d_in[0];
  const float* W_in  = (const float*)d_in[1];
  const float* b_in  = (const float*)d_in[2];
  const float* W_h1  = (const float*)d_in[3];
  const float* b_h1  = (const float*)d_in[4];
  const float* W_12  = (const float*)d_in[5];
  const float* b_12  = (const float*)d_in[6];
  const float* W_h2  = (const float*)d_in[7];
  const float* b_h2  = (const float*)d_in[8];
  const float* W_out = (const float*)d_in[9];
  const float* b_out = (const float*)d_in[10];
  float* out = (float*)d_out;
  float* wsf = (float*)d_ws;

  const size_t XW_FLOATS = (size_t)256 * T_STEPS * H;        // 67,108,864
  const size_t need0 = (XW_FLOATS + TRTOT) * sizeof(float);
  const size_t need1 = (size_t)TRTOT * sizeof(float);

  if (ws_size >= need0) {
    float* xwp = wsf;
    float* tr  = wsf + XW_FLOATS;
    srnn_prep<<<(TRTOT + 255) / 256, 256, 0, stream>>>(W_in, W_h1, W_12, W_h2, W_out, tr);
    srnn_xw2<<<8192, 256, 0, stream>>>(x, tr + WINT_OFF, xwp);
    srnn_scan4<0><<<256, 1024, 0, stream>>>(
        x, xwp, W_in, b_in, b_h1, b_12, b_h2,
        tr, tr + 65792, tr + 131584, tr + WOUT_OFF, b_out, out);
  } else if (ws_size >= need1) {
    float* tr = wsf;
    srnn_prep<<<(TRTOT + 255) / 256, 256, 0, stream>>>(W_in, W_h1, W_12, W_h2, W_out, tr);
    srnn_scan4<1><<<256, 1024, 0, stream>>>(
        x, nullptr, W_in, b_in, b_h1, b_12, b_h2,
        tr, tr + 65792, tr + 131584, tr + WOUT_OFF, b_out, out);
  } else {
    srnn_scan3f<<<256, 1024, 0, stream>>>(
        x, W_in, b_in, b_h1, b_12, b_h2,
        W_h1,  1, H,
        W_12,  1, H,
        W_h2,  1, H,
        W_out, 1, H,
        b_out, out);
  }
}

// Round 16
// 2391.603 us; speedup vs baseline: 2.7839x; 1.0010x over previous
//
#include <hip/hip_runtime.h>

#define T_STEPS 1024
#define N_IN    128
#define H       256
#define N_OUT   64
#define WARM    10

// ===================== R13-validated asm walk =====================
// Index list holds spiking-neuron indices in ASCENDING order, padded to a
// multiple of 32 with index 256 -> a zero row appended to each transposed
// weight matrix (adds +0.0f, an exact identity). Single accumulator, strict
// ascending adds == numpy's dense k-sequential chain. One straight-line asm
// block per 32-slot chunk: 4 sub-batches of 8 loads, 2 in flight, counted
// vmcnt waits. Loads NEVER cross an asm boundary while in flight.

#define DS8 \
  "ds_read_b32 %[a0], %[vL]\n\t"           \
  "ds_read_b32 %[a1], %[vL] offset:4\n\t"  \
  "ds_read_b32 %[a2], %[vL] offset:8\n\t"  \
  "ds_read_b32 %[a3], %[vL] offset:12\n\t" \
  "ds_read_b32 %[a4], %[vL] offset:16\n\t" \
  "ds_read_b32 %[a5], %[vL] offset:20\n\t" \
  "ds_read_b32 %[a6], %[vL] offset:24\n\t" \
  "ds_read_b32 %[a7], %[vL] offset:28\n\t" \
  "v_add_u32 %[vL], 32, %[vL]\n\t"

#define LD8(P, SHSTR) \
  "s_waitcnt lgkmcnt(0)\n\t" \
  "v_lshl_add_u32 %[a0], %[a0], " SHSTR ", %[vi]\n\t" \
  "v_lshl_add_u32 %[a1], %[a1], " SHSTR ", %[vi]\n\t" \
  "v_lshl_add_u32 %[a2], %[a2], " SHSTR ", %[vi]\n\t" \
  "v_lshl_add_u32 %[a3], %[a3], " SHSTR ", %[vi]\n\t" \
  "v_lshl_add_u32 %[a4], %[a4], " SHSTR ", %[vi]\n\t" \
  "v_lshl_add_u32 %[a5], %[a5], " SHSTR ", %[vi]\n\t" \
  "v_lshl_add_u32 %[a6], %[a6], " SHSTR ", %[vi]\n\t" \
  "v_lshl_add_u32 %[a7], %[a7], " SHSTR ", %[vi]\n\t" \
  "global_load_dword %[" #P "0], %[a0], %[wb]\n\t" \
  "global_load_dword %[" #P "1], %[a1], %[wb]\n\t" \
  "global_load_dword %[" #P "2], %[a2], %[wb]\n\t" \
  "global_load_dword %[" #P "3], %[a3], %[wb]\n\t" \
  "global_load_dword %[" #P "4], %[a4], %[wb]\n\t" \
  "global_load_dword %[" #P "5], %[a5], %[wb]\n\t" \
  "global_load_dword %[" #P "6], %[a6], %[wb]\n\t" \
  "global_load_dword %[" #P "7], %[a7], %[wb]\n\t"

#define ADD8(P) \
  "v_add_f32 %[ac], %[ac], %[" #P "0]\n\t" \
  "v_add_f32 %[ac], %[ac], %[" #P "1]\n\t" \
  "v_add_f32 %[ac], %[ac], %[" #P "2]\n\t" \
  "v_add_f32 %[ac], %[ac], %[" #P "3]\n\t" \
  "v_add_f32 %[ac], %[ac], %[" #P "4]\n\t" \
  "v_add_f32 %[ac], %[ac], %[" #P "5]\n\t" \
  "v_add_f32 %[ac], %[ac], %[" #P "6]\n\t" \
  "v_add_f32 %[ac], %[ac], %[" #P "7]\n\t"

#define DEF_WALK(NAME, SHSTR)                                              \
__device__ __forceinline__ float NAME(const int* lidx, int n,              \
                                      const float* wbase, int i4) {        \
  float acc = 0.0f;                                                        \
  int nc = (n + 31) >> 5;                                                  \
  unsigned vL = (unsigned)(unsigned long long)lidx;  /* low32 = LDS off */ \
  for (int c = 0; c < nc; ++c) {                                           \
    float a0,a1,a2,a3,a4,a5,a6,a7;                                         \
    float d0,d1,d2,d3,d4,d5,d6,d7;                                         \
    float e0,e1,e2,e3,e4,e5,e6,e7;                                         \
    asm volatile(                                                          \
      DS8                      /* sb0 idx */                               \
      LD8(d, SHSTR)            /* sb0 -> d (8 in flight) */                \
      DS8                      /* sb1 idx */                               \
      LD8(e, SHSTR)            /* sb1 -> e (16) */                         \
      DS8                      /* sb2 idx prefetch */                      \
      "s_waitcnt vmcnt(8)\n\t" /* sb0 done */                              \
      ADD8(d)                                                              \
      LD8(d, SHSTR)            /* sb2 -> d (16) */                         \
      DS8                      /* sb3 idx prefetch */                      \
      "s_waitcnt vmcnt(8)\n\t" /* sb1 done */                              \
      ADD8(e)                                                              \
      LD8(e, SHSTR)            /* sb3 -> e (16) */                         \
      "s_waitcnt vmcnt(8)\n\t" /* sb2 done */                              \
      ADD8(d)                                                              \
      "s_waitcnt vmcnt(0)\n\t" /* sb3 done */                              \
      ADD8(e)                                                              \
      : [a0]"=&v"(a0), [a1]"=&v"(a1), [a2]"=&v"(a2), [a3]"=&v"(a3),        \
        [a4]"=&v"(a4), [a5]"=&v"(a5), [a6]"=&v"(a6), [a7]"=&v"(a7),        \
        [d0]"=&v"(d0), [d1]"=&v"(d1), [d2]"=&v"(d2), [d3]"=&v"(d3),        \
        [d4]"=&v"(d4), [d5]"=&v"(d5), [d6]"=&v"(d6), [d7]"=&v"(d7),        \
        [e0]"=&v"(e0), [e1]"=&v"(e1), [e2]"=&v"(e2), [e3]"=&v"(e3),        \
        [e4]"=&v"(e4), [e5]"=&v"(e5), [e6]"=&v"(e6), [e7]"=&v"(e7),        \
        [ac]"+v"(acc), [vL]"+v"(vL)                                        \
      : [vi]"v"(i4), [wb]"s"(wbase)                                        \
      : "memory");                                                         \
  }                                                                        \
  return acc;                                                              \
}

DEF_WALK(walk_sh10, "10")   // rows of 256 floats (1024 B)
DEF_WALK(walk_sh8,  "8")    // rows of 64 floats (256 B, WoutT)

// ---------- R11-validated fallback walk (tiny-ws path only) ----------
__device__ __forceinline__ float walk16(const unsigned long long* __restrict__ m4,
                                        const float* __restrict__ base,
                                        int sjj, int sii, int i) {
  float a = 0.f;
#pragma unroll
  for (int w = 0; w < 4; ++w) {
    unsigned long long m = m4[w];
    const float* bp = base + (size_t)(w * 64) * sjj + (size_t)i * sii;
    while (m) {
      float t0,t1,t2,t3,t4,t5,t6,t7,t8,t9,t10,t11,t12,t13,t14,t15;
#define GRAB(tk) { int j = m ? (__ffsll(m) - 1) : 0;            \
                   float v = bp[(size_t)j * sjj];               \
                   tk = m ? v : 0.0f;                           \
                   m &= m - 1; }
      GRAB(t0)  GRAB(t1)  GRAB(t2)  GRAB(t3)
      GRAB(t4)  GRAB(t5)  GRAB(t6)  GRAB(t7)
      GRAB(t8)  GRAB(t9)  GRAB(t10) GRAB(t11)
      GRAB(t12) GRAB(t13) GRAB(t14) GRAB(t15)
#undef GRAB
      a += t0;  a += t1;  a += t2;  a += t3;
      a += t4;  a += t5;  a += t6;  a += t7;
      a += t8;  a += t9;  a += t10; a += t11;
      a += t12; a += t13; a += t14; a += t15;
    }
  }
  return a;
}

// ---------- prep: transposed weights (+ zero rows) + WinT ----------
// ws floats (relative to tr base):
//   Wh1T @0 (257*256) | W12T @65792 | Wh2T @131584 | WoutT @197376 (257*64)
//   WinT @213824 (128 rows of 256: WinT[k][i] = W_in[i][k])   total 246592
#define WOUT_OFF 197376
#define WINT_OFF 213824
#define TRTOT    246592
__global__ void srnn_prep(const float* __restrict__ Win,
                          const float* __restrict__ Wh1,
                          const float* __restrict__ W12,
                          const float* __restrict__ Wh2,
                          const float* __restrict__ Wout,
                          float* __restrict__ ws) {
  int idx = blockIdx.x * 256 + (int)threadIdx.x;
  if (idx >= TRTOT) return;
  if (idx < 3 * 65792) {
    int mat = idx / 65792;
    int rem = idx - mat * 65792;
    int j = rem >> 8, i = rem & 255;
    const float* src = (mat == 0) ? Wh1 : (mat == 1) ? W12 : Wh2;
    ws[idx] = (j < H) ? src[i * H + j] : 0.0f;
  } else if (idx < WINT_OFF) {
    int rem = idx - WOUT_OFF;
    int j = rem >> 6, o = rem & 63;
    ws[idx] = (j < H) ? Wout[o * H + j] : 0.0f;
  } else {
    int rem = idx - WINT_OFF;
    int k = rem >> 8, i = rem & 255;
    ws[idx] = Win[i * N_IN + k];                  // WinT[k][i]
  }
}

// ---------- xw precompute, occupancy-fixed: 16KB LDS, many blocks/CU ----------
// Chain per (row,i): single accumulator, k ascending, fmaf — bit-identical
// to the validated in-scan chain.
__launch_bounds__(256)
__global__ void srnn_xw2(const float* __restrict__ x,
                         const float* __restrict__ WinT,
                         float* __restrict__ xw) {
  __shared__ float xt[32][N_IN];                  // 16 KB
  const int tid = (int)threadIdx.x;
  const int b  = (int)blockIdx.x >> 5;
  const int t0 = ((int)blockIdx.x & 31) * 32;
  {
    const float4* src = reinterpret_cast<const float4*>(
        x + ((size_t)b * T_STEPS + t0) * N_IN);
    float4* dst = reinterpret_cast<float4*>(&xt[0][0]);
    for (int q = tid; q < 32 * N_IN / 4; q += 256) dst[q] = src[q];
  }
  __syncthreads();
  const int i = tid;
  float a[32];
#pragma unroll
  for (int r = 0; r < 32; ++r) a[r] = 0.f;
#pragma unroll 4
  for (int k = 0; k < N_IN; ++k) {
    float w = WinT[k * H + i];                    // coalesced, L2-hot
#pragma unroll
    for (int r = 0; r < 32; ++r) a[r] = fmaf(xt[r][k], w, a[r]);
  }
  float* dst = xw + ((size_t)b * T_STEPS + t0) * H + i;
#pragma unroll
  for (int r = 0; r < 32; ++r) dst[(size_t)r * H] = a[r];
}

// ---------- main scan (R13-validated): L (4 walks) / M / C ----------
#define BUILD_LISTS()                                                           \
  if (tid < 512) {                                                              \
    const bool l1 = tid < 256;                                                  \
    const int  tt = tid & 255;                                                  \
    const int  w  = tt >> 6, l = tt & 63;                                       \
    unsigned long long mw = l1 ? s1m[w] : s2m[w];                               \
    const int* cp = l1 ? cnt1 : cnt2;                                           \
    int* lst = l1 ? idxL1 : idxL2;                                              \
    int base = (w > 0 ? cp[0] : 0) + (w > 1 ? cp[1] : 0) + (w > 2 ? cp[2] : 0); \
    int rank = base + (int)__popcll(mw & ((1ull << l) - 1ull));                 \
    if ((mw >> l) & 1ull) lst[rank] = tt;                                       \
    if (tt < 32) {                                                              \
      int ntot = cp[0] + cp[1] + cp[2] + cp[3];                                 \
      lst[ntot + tt] = 256;                                                     \
      if (tt == 0) { if (l1) n1s = ntot; else n2s = ntot; }                     \
    }                                                                           \
  }

template<int MODE>   // 0: xw precomputed; 1: in-scan x-dot via win_lds
__launch_bounds__(1024)
__global__ void srnn_scan4(const float* __restrict__ x,
                           const float* __restrict__ xw,
                           const float* __restrict__ Win,
                           const float* __restrict__ bin_p, const float* __restrict__ bh1_p,
                           const float* __restrict__ b12_p, const float* __restrict__ bh2_p,
                           const float* __restrict__ Wh1b,
                           const float* __restrict__ W12b,
                           const float* __restrict__ Wh2b,
                           const float* __restrict__ Wob,
                           const float* __restrict__ bo_p,
                           float* __restrict__ out) {
  __shared__ float h1d[H], h2d[H];
  __shared__ unsigned long long s1m[4], s2m[4];
  __shared__ int cnt1[4], cnt2[4];
  __shared__ int idxL1[H + 32], idxL2[H + 32];
  __shared__ int n1s, n2s;
  __shared__ float win_lds[(MODE == 1) ? (N_IN * 257) : 1];
  __shared__ float xs[(MODE == 1) ? 2 : 1][N_IN];

  const int tid = (int)threadIdx.x;
  const int g   = tid >> 8;
  const int i   = tid & 255;
  const int bb  = (int)blockIdx.x;

  if (MODE == 1) {
    for (int q = tid; q < H * N_IN; q += 1024) {
      int i2 = q >> 7, k = q & (N_IN - 1);
      win_lds[k * 257 + i2] = Win[q];
    }
    if (tid < N_IN) xs[0][tid] = x[(size_t)bb * (T_STEPS * N_IN) + tid];
  }
  if (tid < 4) { s2m[tid] = 0ull; cnt2[tid] = 0; cnt1[tid] = 0; }

  const float bin_i = (tid < H) ? bin_p[i] : 0.f;
  const float bh1_i = (tid < H) ? bh1_p[i] : 0.f;
  const float b12_i = (tid < H) ? b12_p[i] : 0.f;
  const float bh2_i = (tid < H) ? bh2_p[i] : 0.f;
  const float bo_o  = (g == 3 && i < N_OUT) ? bo_p[i] : 0.f;

  float m1 = 0.f, m2 = 0.f, acc = 0.f, c12v = 0.f, xv_next = 0.f;

  __syncthreads();

  // ---- prologue: u1(0) (h1 term is exactly +0.0), ballot s1(0)
  if (tid < H) {
    float xv0;
    if (MODE == 0) {
      xv0     = xw[((size_t)bb * T_STEPS + 0) * H + i];
      xv_next = xw[((size_t)bb * T_STEPS + 1) * H + i];
    } else {
      float a = 0.f;
#pragma unroll 16
      for (int k = 0; k < N_IN; ++k)
        a = fmaf(xs[0][k], win_lds[k * 257 + i], a);
      xv0 = a;
    }
    float u1 = 0.9f * m1;
    u1 = u1 + xv0;
    u1 = u1 + bin_i;
    u1 = u1 + 0.0f;
    u1 = u1 + bh1_i;
    bool sp = (u1 - 1.0f) > 0.0f;
    m1 = u1 - (sp ? 1.0f : 0.0f);
    unsigned long long bm = __ballot(sp);
    if ((tid & 63) == 0) { s1m[tid >> 6] = bm; cnt1[tid >> 6] = (int)__popcll(bm); }
  }
  __syncthreads();
  BUILD_LISTS();
  __syncthreads();

  for (int t = 0; t < T_STEPS; ++t) {
    // ---- L(t): four concurrent walks over compact lists
    if (g == 0) {
      c12v = walk_sh10(idxL1, n1s, W12b, i * 4);             // s1(t) -> layer2
    } else if (g == 1) {
      h2d[i] = walk_sh10(idxL2, n2s, Wh2b, i * 4);           // s2(t-1)
    } else if (g == 2) {
      h1d[i] = walk_sh10(idxL1, n1s, Wh1b, i * 4);           // s1(t) -> u1(t+1)
    } else {
      if (i < N_OUT) {
        if (t > WARM) {                                      // readout of s2(t-1)
          float d = walk_sh8(idxL2, n2s, Wob, i * 4);
          acc = acc + (d + bo_o);
        }
      } else if (MODE == 1 && i >= 64 && i < 64 + N_IN && t + 1 < T_STEPS) {
        xs[(t & 1) ^ 1][i - 64] =
            x[(size_t)bb * (T_STEPS * N_IN) + (size_t)(t + 1) * N_IN + (i - 64)];
      }
    }
    __syncthreads();

    // ---- M(t): u2(t) then u1(t+1) (validated left-assoc chains)
    if (tid < H) {
      float u2 = 0.9f * m2;
      u2 = u2 + c12v;
      u2 = u2 + b12_i;
      u2 = u2 + h2d[i];
      u2 = u2 + bh2_i;
      bool sp2 = (u2 - 1.0f) > 0.0f;
      m2 = u2 - (sp2 ? 1.0f : 0.0f);
      unsigned long long bm2 = __ballot(sp2);
      if ((tid & 63) == 0) { s2m[tid >> 6] = bm2; cnt2[tid >> 6] = (int)__popcll(bm2); }

      if (t + 1 < T_STEPS) {
        float xv;
        if (MODE == 0) {
          xv = xv_next;
        } else {
          float a = 0.f;
#pragma unroll 16
          for (int k = 0; k < N_IN; ++k)
            a = fmaf(xs[(t & 1) ^ 1][k], win_lds[k * 257 + i], a);
          xv = a;
        }
        float u1 = 0.9f * m1;
        u1 = u1 + xv;
        u1 = u1 + bin_i;
        u1 = u1 + h1d[i];
        u1 = u1 + bh1_i;
        bool sp1 = (u1 - 1.0f) > 0.0f;
        m1 = u1 - (sp1 ? 1.0f : 0.0f);
        unsigned long long bm1 = __ballot(sp1);
        if ((tid & 63) == 0) { s1m[tid >> 6] = bm1; cnt1[tid >> 6] = (int)__popcll(bm1); }
        if (MODE == 0 && t + 2 < T_STEPS)
          xv_next = xw[((size_t)bb * T_STEPS + (t + 2)) * H + i];
      }
    }
    __syncthreads();

    // ---- C(t): rank-compaction of the fresh ballots into flat ascending lists
    BUILD_LISTS();
    __syncthreads();
  }

  // ---- epilogue: readout of s2(1023) (idxL2 built in C(1023))
  if (g == 3 && i < N_OUT) {
    float d = walk_sh8(idxL2, n2s, Wob, i * 4);
    acc = acc + (d + bo_o);
    out[(size_t)bb * N_OUT + i] = acc / 1014.0f;
  }
}

// ---------- R11-validated fallback scan (tiny-ws path, original layouts) ----------
__launch_bounds__(1024)
__global__ void srnn_scan3f(const float* __restrict__ x,
                            const float* __restrict__ Win,
                            const float* __restrict__ bin_p, const float* __restrict__ bh1_p,
                            const float* __restrict__ b12_p, const float* __restrict__ bh2_p,
                            const float* __restrict__ Wh1b, int h1j, int h1i,
                            const float* __restrict__ W12b, int c12j, int c12i,
                            const float* __restrict__ Wh2b, int h2j, int h2i,
                            const float* __restrict__ Wob,  int woj, int woi,
                            const float* __restrict__ bo_p,
                            float* __restrict__ out) {
  __shared__ float h1d[H], h2d[H];
  __shared__ unsigned long long s1m[2][4], s2m[2][4];
  __shared__ float win_lds[N_IN * 257];
  __shared__ float xs[2][N_IN];

  const int tid = (int)threadIdx.x;
  const int g   = tid >> 8;
  const int i   = tid & 255;
  const int b   = (int)blockIdx.x;

  for (int q = tid; q < H * N_IN; q += 1024) {
    int i2 = q >> 7, k = q & (N_IN - 1);
    win_lds[k * 257 + i2] = Win[q];
  }
  if (tid < N_IN) xs[0][tid] = x[(size_t)b * (T_STEPS * N_IN) + tid];
  if (tid < 4)       { s1m[0][tid] = 0ull; s2m[0][tid] = 0ull; }
  else if (tid < 8)  { s1m[1][tid - 4] = 0ull; s2m[1][tid - 4] = 0ull; }

  const float bin_i = (tid < H) ? bin_p[i] : 0.f;
  const float bh1_i = (tid < H) ? bh1_p[i] : 0.f;
  const float b12_i = (tid < H) ? b12_p[i] : 0.f;
  const float bh2_i = (tid < H) ? bh2_p[i] : 0.f;
  const float bo_o  = (g == 3 && i < N_OUT) ? bo_p[i] : 0.f;

  float m1 = 0.f, m2 = 0.f, acc = 0.f, c12v = 0.f;

  __syncthreads();

  if (tid < H) {
    float a = 0.f;
#pragma unroll 16
    for (int k = 0; k < N_IN; ++k)
      a = fmaf(xs[0][k], win_lds[k * 257 + i], a);
    float u1 = 0.9f * m1;
    u1 = u1 + a;
    u1 = u1 + bin_i;
    u1 = u1 + 0.0f;
    u1 = u1 + bh1_i;
    bool sp = (u1 - 1.0f) > 0.0f;
    m1 = u1 - (sp ? 1.0f : 0.0f);
    unsigned long long bm = __ballot(sp);
    if ((tid & 63) == 0) s1m[0][tid >> 6] = bm;
  }
  __syncthreads();

  for (int t = 0; t < T_STEPS; ++t) {
    const int cb = t & 1;
    const int pb = cb ^ 1;
    if (g == 0) {
      c12v = walk16(s1m[cb], W12b, c12j, c12i, i);
    } else if (g == 1) {
      h2d[i] = walk16(s2m[pb], Wh2b, h2j, h2i, i);
    } else if (g == 2) {
      h1d[i] = walk16(s1m[cb], Wh1b, h1j, h1i, i);
    } else {
      if (i < N_OUT) {
        if (t > WARM) {
          float d = walk16(s2m[pb], Wob, woj, woi, i);
          acc = acc + (d + bo_o);
        }
      } else if (i >= 64 && i < 64 + N_IN && t + 1 < T_STEPS) {
        xs[pb][i - 64] = x[(size_t)b * (T_STEPS * N_IN) + (size_t)(t + 1) * N_IN + (i - 64)];
      }
    }
    __syncthreads();
    if (tid < H) {
      float u2 = 0.9f * m2;
      u2 = u2 + c12v;
      u2 = u2 + b12_i;
      u2 = u2 + h2d[i];
      u2 = u2 + bh2_i;
      bool sp2 = (u2 - 1.0f) > 0.0f;
      m2 = u2 - (sp2 ? 1.0f : 0.0f);
      unsigned long long bm2 = __ballot(sp2);
      if ((tid & 63) == 0) s2m[cb][tid >> 6] = bm2;
      if (t + 1 < T_STEPS) {
        float a = 0.f;
#pragma unroll 16
        for (int k = 0; k < N_IN; ++k)
          a = fmaf(xs[pb][k], win_lds[k * 257 + i], a);
        float u1 = 0.9f * m1;
        u1 = u1 + a;
        u1 = u1 + bin_i;
        u1 = u1 + h1d[i];
        u1 = u1 + bh1_i;
        bool sp1 = (u1 - 1.0f) > 0.0f;
        m1 = u1 - (sp1 ? 1.0f : 0.0f);
        unsigned long long bm1 = __ballot(sp1);
        if ((tid & 63) == 0) s1m[pb][tid >> 6] = bm1;
      }
    }
    __syncthreads();
  }

  if (g == 3 && i < N_OUT) {
    float d = walk16(s2m[1], Wob, woj, woi, i);
    acc = acc + (d + bo_o);
    out[(size_t)b * N_OUT + i] = acc / 1014.0f;
  }
}

// ---------- launch ----------
extern "C" void kernel_launch(void* const* d_in, const int* in_sizes, int n_in,
                              void* d_out, int out_size, void* d_ws, size_t ws_size,
                              hipStream_t stream) {
  const float* x     = (const float*)d_in[0];
  const float* W_in  = (const float*)d_in[1];
  const float* b_in  = (const float*)d_in[2];
  const float* W_h1  = (const float*)d_in[3];
  const float* b_h1  = (const float*)d_in[4];
  const float* W_12  = (const float*)d_in[5];
  const float* b_12  = (const float*)d_in[6];
  const float* W_h2  = (const float*)d_in[7];
  const float* b_h2  = (const float*)d_in[8];
  const float* W_out = (const float*)d_in[9];
  const float* b_out = (const float*)d_in[10];
  float* out = (float*)d_out;
  float* wsf = (float*)d_ws;

  const size_t XW_FLOATS = (size_t)256 * T_STEPS * H;        // 67,108,864
  const size_t need0 = (XW_FLOATS + TRTOT) * sizeof(float);
  const size_t need1 = (size_t)TRTOT * sizeof(float);

  if (ws_size >= need0) {
    float* xwp = wsf;
    float* tr  = wsf + XW_FLOATS;
    srnn_prep<<<(TRTOT + 255) / 256, 256, 0, stream>>>(W_in, W_h1, W_12, W_h2, W_out, tr);
    srnn_xw2<<<8192, 256, 0, stream>>>(x, tr + WINT_OFF, xwp);
    srnn_scan4<0><<<256, 1024, 0, stream>>>(
        x, xwp, W_in, b_in, b_h1, b_12, b_h2,
        tr, tr + 65792, tr + 131584, tr + WOUT_OFF, b_out, out);
  } else if (ws_size >= need1) {
    float* tr = wsf;
    srnn_prep<<<(TRTOT + 255) / 256, 256, 0, stream>>>(W_in, W_h1, W_12, W_h2, W_out, tr);
    srnn_scan4<1><<<256, 1024, 0, stream>>>(
        x, nullptr, W_in, b_in, b_h1, b_12, b_h2,
        tr, tr + 65792, tr + 131584, tr + WOUT_OFF, b_out, out);
  } else {
    srnn_scan3f<<<256, 1024, 0, stream>>>(
        x, W_in, b_in, b_h1, b_12, b_h2,
        W_h1,  1, H,
        W_12,  1, H,
        W_h2,  1, H,
        W_out, 1, H,
        b_out, out);
  }
}